// Round 13
// baseline (3445.794 us; speedup 1.0000x reference)
//
#include <hip/hip_runtime.h>

typedef int i32x4  __attribute__((ext_vector_type(4)));
typedef int i32x16 __attribute__((ext_vector_type(16)));

#define NBLK 1024u

// ---------------- prep: all weight quant/pack + wsum + barrier init, ONE dispatch ----------------
// wqH [27][32] fp32 ; WpB 12x[9][64][16] i8 ; WpT [9][64][16] i8 ; wsum [13][32] ; bar[0]=cnt bar[32]=gen
__global__ __launch_bounds__(256) void prep_kernel(
    const float* __restrict__ head_w, const float* __restrict__ head_sw,
    const float* __restrict__ bb_w,   const float* __restrict__ bb_sw,
    const float* __restrict__ tr_w,   const float* __restrict__ tr_sw,
    float* __restrict__ wqH, signed char* __restrict__ WpB,
    signed char* __restrict__ WpT, float* __restrict__ wsum,
    unsigned* __restrict__ bar)
{
    int i = blockIdx.x * 256 + threadIdx.x;
    if (i == 0) { bar[0] = 0u; bar[32] = 0u; }
    if (i < 864) {
        int oc = i / 27, k = i - oc * 27;
        float v = rintf(head_w[i] / head_sw[0]);
        v = fminf(fmaxf(v, -127.f), 127.f);
        wqH[k * 32 + oc] = v;
    } else if (i < 111456) {
        int j = i - 864;
        int l = j / 9216, r = j - l * 9216;
        int tap = r >> 10, r2 = r & 1023, lane = r2 >> 4, jj = r2 & 15;
        int oc = lane & 31, ic = ((lane >> 5) << 4) + jj;
        float q = rintf(bb_w[((l * 32 + oc) * 32 + ic) * 9 + tap] / bb_sw[l]);
        q = fminf(fmaxf(q, -127.f), 127.f);
        WpB[j] = (signed char)(int)q;
    } else if (i < 120672) {
        int j = i - 111456;
        int tap = j >> 10, r2 = j & 1023, lane = r2 >> 4, jj = r2 & 15;
        int oc = lane & 31, ic = ((lane >> 5) << 4) + jj;
        signed char v = 0;
        if (oc < 12) {
            float q = rintf(tr_w[(oc * 32 + ic) * 9 + tap] / tr_sw[0]);
            q = fminf(fmaxf(q, -127.f), 127.f);
            v = (signed char)(int)q;
        }
        WpT[j] = v;
    } else if (i < 121088) {
        int t = i - 120672;
        int l = t >> 5, oc = t & 31;
        float sum = 0.f;
        if (l < 12) {
            for (int k = 0; k < 288; ++k) {
                float q = rintf(bb_w[(l * 32 + oc) * 288 + k] / bb_sw[l]);
                sum += fminf(fmaxf(q, -127.f), 127.f);
            }
        } else if (oc < 12) {
            for (int k = 0; k < 288; ++k) {
                float q = rintf(tr_w[oc * 288 + k] / tr_sw[0]);
                sum += fminf(fmaxf(q, -127.f), 127.f);
            }
        }
        wsum[t] = sum;
    }
}

// ---------------- global barrier: sense-reversing, device scope ----------------
__device__ __forceinline__ void gbar(unsigned* cnt, unsigned* gen)
{
    __syncthreads();
    if (threadIdx.x == 0) {
        __threadfence();   // release this block's writes (agent scope)
        unsigned g = __hip_atomic_load(gen, __ATOMIC_RELAXED, __HIP_MEMORY_SCOPE_AGENT);
        unsigned a = __hip_atomic_fetch_add(cnt, 1u, __ATOMIC_ACQ_REL, __HIP_MEMORY_SCOPE_AGENT);
        if (a == NBLK - 1u) {
            __hip_atomic_store(cnt, 0u, __ATOMIC_RELAXED, __HIP_MEMORY_SCOPE_AGENT);
            __hip_atomic_fetch_add(gen, 1u, __ATOMIC_RELEASE, __HIP_MEMORY_SCOPE_AGENT);
        } else {
            int guard = 0;
            while (__hip_atomic_load(gen, __ATOMIC_ACQUIRE, __HIP_MEMORY_SCOPE_AGENT) == g) {
                __builtin_amdgcn_s_sleep(8);
                if (++guard > 4000000) break;   // bounded: fail loud (wrong data), not hang
            }
        }
    }
    __syncthreads();
    __threadfence();       // acquire side for all threads of the block
}

// ---------------- megakernel: head + 12 backbone + tail, one dispatch, persistent blocks ----------------
// grid (8,16,8)=1024 blocks, 256 thr; LDS 19.6KB; capacity 2048 blocks => all resident (barrier-safe).
__global__ __launch_bounds__(256, 4) void mega_kernel(
    const float* __restrict__ x,
    const float* __restrict__ wqH, const float* __restrict__ head_b,
    const float* __restrict__ head_sw,
    const signed char* __restrict__ WpB, const float* __restrict__ bb_b,
    const float* __restrict__ bb_sw,
    const signed char* __restrict__ WpT, const float* __restrict__ tr_b,
    const float* __restrict__ tr_sw,
    const float* __restrict__ wsum, const float* __restrict__ s_ptr,
    unsigned char* __restrict__ buf0, unsigned char* __restrict__ buf1,
    unsigned char* __restrict__ buf2,
    unsigned* __restrict__ bar,
    float* __restrict__ out)
{
    __shared__ unsigned char aT[19584];   // layers: 18*68*16 ; head reuses first 1836 B
    const int tid = threadIdx.x;
    const int x0 = blockIdx.x << 5;
    const int y0 = blockIdx.y << 4;
    const int b  = blockIdx.z;
    const float s = s_ptr[0];
    unsigned* cnt = bar;
    unsigned* gen = bar + 32;

    // ================= head: this block's 32x16 tile of buf0 =================
    {
        for (int p = tid; p < 1836; p += 256) {
            int ch = p / 612, rem = p - ch * 612;
            int r = rem / 34, c = rem - r * 34;
            int gy = y0 + r - 1, gx = x0 + c - 1;
            unsigned char v = 0;
            if ((unsigned)gy < 256u && (unsigned)gx < 256u) {
                float xv = x[((b * 3 + ch) << 16) + (gy << 8) + gx];
                float q = (s == 1.0f) ? xv : (xv / s);
                q = rintf(q);
                q = fminf(fmaxf(q, 0.0f), 255.0f);
                v = (unsigned char)q;
            }
            ((unsigned char*)aT)[(ch * 18 + r) * 34 + c] = v;
        }
        __syncthreads();

        const int c = tid & 31;
        const int r0 = tid >> 5;
        const float alpha = s * head_sw[0];
        #pragma unroll
        for (int half = 0; half < 2; ++half) {
            const int r = r0 + half * 8;
            float acc[32];
            #pragma unroll
            for (int i = 0; i < 32; ++i) acc[i] = 0.0f;
            #pragma unroll
            for (int ic = 0; ic < 3; ++ic) {
                float a[9];
                #pragma unroll
                for (int dy = 0; dy < 3; ++dy)
                    #pragma unroll
                    for (int dx = 0; dx < 3; ++dx)
                        a[dy * 3 + dx] = (float)((unsigned char*)aT)[(ic * 18 + r + dy) * 34 + c + dx];
                #pragma unroll
                for (int t = 0; t < 9; ++t) {
                    const float* wrow = wqH + (ic * 9 + t) * 32;
                    #pragma unroll
                    for (int oc = 0; oc < 32; ++oc)
                        acc[oc] = fmaf(a[t], wrow[oc], acc[oc]);
                }
            }
            unsigned int w8[8] = {0,0,0,0,0,0,0,0};
            #pragma unroll
            for (int oc = 0; oc < 32; ++oc) {
                float y = fmaf(alpha, acc[oc], head_b[oc]);
                y = fmaxf(y, 0.0f);
                float v = (s == 1.0f) ? y : (y / s);
                v = rintf(v);
                v = fminf(fmaxf(v, 0.0f), 255.0f);
                w8[oc >> 2] |= ((unsigned int)(unsigned char)v) << (8 * (oc & 3));
            }
            uint4* dst = (uint4*)(buf0 + (size_t)((((b << 8) + (y0 + r)) << 8) + (x0 + c)) * 32);
            dst[0] = make_uint4(w8[0]^0x80808080u, w8[1]^0x80808080u, w8[2]^0x80808080u, w8[3]^0x80808080u);
            dst[1] = make_uint4(w8[4]^0x80808080u, w8[5]^0x80808080u, w8[6]^0x80808080u, w8[7]^0x80808080u);
        }
    }
    gbar(cnt, gen);   // buf0 complete device-wide

    // ================= 12 backbone layers + tail =================
    #pragma unroll 1
    for (int l = 0; l < 13; ++l) {
        const bool fin = (l == 12);
        const unsigned char* src = (l == 0) ? buf0 : ((l & 1) ? buf1 : buf2);
        unsigned char* dst8 = (l & 1) ? buf2 : buf1;
        const signed char* Wp = fin ? WpT : (WpB + l * 9216);
        const float* bias = fin ? tr_b : (bb_b + l * 32);
        const float* wsp  = fin ? (wsum + 384) : (wsum + l * 32);
        const float alpha = s * (fin ? tr_sw[0] : bb_sw[l]);

        // ---- stage (16B copies of biased codes; residual add if fin) ----
        #pragma unroll
        for (int it = 0; it < 5; ++it) {
            int ci = tid + it * 256;
            if (ci < 1224) {
                int row = (ci * 241) >> 14;
                int rem = ci - row * 68;
                int xt = rem >> 1, hf = rem & 1;
                int gy = y0 + row - 1, gx = x0 + xt - 1;
                uint4 v = make_uint4(0x80808080u, 0x80808080u, 0x80808080u, 0x80808080u);
                if ((unsigned)gy < 256u && (unsigned)gx < 256u) {
                    size_t off = (size_t)((((b << 8) + gy) << 8) + gx) * 32 + (hf << 4);
                    v = *(const uint4*)(src + off);
                    if (fin) {
                        uint4 rv = *(const uint4*)(buf0 + off);
                        unsigned int* vp = (unsigned int*)&v;
                        const unsigned int* rp = (const unsigned int*)&rv;
                        #pragma unroll
                        for (int w = 0; w < 4; ++w) {
                            unsigned int xw = vp[w], yw = rp[w], ow = 0;
                            #pragma unroll
                            for (int bb = 0; bb < 4; ++bb) {
                                int xs = (int)(signed char)(xw >> (8 * bb));
                                int ys = (int)(signed char)(yw >> (8 * bb));
                                int t = xs + ys + 128;
                                if (t > 127) t = 127;
                                ow |= ((unsigned int)(t & 255)) << (8 * bb);
                            }
                            vp[w] = ow;
                        }
                    }
                }
                int cs = rem ^ ((rem >> 3) & 7);
                *(uint4*)&aT[(row * 68 + cs) << 4] = v;
            }
        }
        __syncthreads();

        // ---- compute: D = W * Act^T via mfma_i32_32x32x32_i8 ----
        const int lane = tid & 63;
        const int wid  = tid >> 6;
        const int px   = lane & 31;
        const int khf  = lane >> 5;
        const int py0  = wid << 2;
        const int gx   = x0 + px;

        i32x16 acc[4];
        #pragma unroll
        for (int p = 0; p < 4; ++p)
            #pragma unroll
            for (int i = 0; i < 16; ++i) acc[p][i] = 0;

        #pragma unroll
        for (int dx = 0; dx < 3; ++dx) {
            const int c  = ((px + dx) << 1) + khf;
            const int cs = c ^ ((c >> 3) & 7);
            i32x4 af[6];
            #pragma unroll
            for (int yl = 0; yl < 6; ++yl)
                af[yl] = *(const i32x4*)&aT[((py0 + yl) * 68 + cs) << 4];
            #pragma unroll
            for (int dy = 0; dy < 3; ++dy) {
                i32x4 wf = *(const i32x4*)(Wp + ((((dy * 3 + dx) << 6) + lane) << 4));
                acc[0] = __builtin_amdgcn_mfma_i32_32x32x32_i8(wf, af[0 + dy], acc[0], 0, 0, 0);
                acc[1] = __builtin_amdgcn_mfma_i32_32x32x32_i8(wf, af[1 + dy], acc[1], 0, 0, 0);
                acc[2] = __builtin_amdgcn_mfma_i32_32x32x32_i8(wf, af[2 + dy], acc[2], 0, 0, 0);
                acc[3] = __builtin_amdgcn_mfma_i32_32x32x32_i8(wf, af[3 + dy], acc[3], 0, 0, 0);
            }
        }

        // ---- epilogue ----
        if (!fin) {
            float bv[16];
            #pragma unroll
            for (int r = 0; r < 16; ++r) {
                const int oc = (r & 3) + ((r >> 2) << 3) + (khf << 2);
                bv[r] = fmaf(alpha * 128.0f, wsp[oc], bias[oc]);
            }
            #pragma unroll
            for (int py = 0; py < 4; ++py) {
                const int gy = y0 + py0 + py;
                unsigned char* pout = dst8 + (((size_t)((((b << 8) + gy) << 8) + gx)) << 5);
                #pragma unroll
                for (int q = 0; q < 4; ++q) {
                    unsigned int wv = 0;
                    #pragma unroll
                    for (int j = 0; j < 4; ++j) {
                        float y = fmaf(alpha, (float)acc[py][4 * q + j], bv[4 * q + j]);
                        y = fmaxf(y, 0.0f);
                        float v = (s == 1.0f) ? y : (y / s);
                        v = rintf(v);
                        v = fminf(fmaxf(v, 0.0f), 255.0f);
                        wv |= ((unsigned int)v) << (8 * j);
                    }
                    *(unsigned int*)(pout + 8 * q + 4 * khf) = wv ^ 0x80808080u;
                }
            }
            gbar(cnt, gen);
        } else {
            #pragma unroll
            for (int py = 0; py < 4; ++py) {
                const int gy = y0 + py0 + py;
                #pragma unroll
                for (int r = 0; r < 16; ++r) {
                    const int oc = (r & 3) + ((r >> 2) << 3) + (khf << 2);
                    if (oc < 12) {
                        float y = fmaf(alpha, (float)acc[py][r],
                                       fmaf(alpha * 128.0f, wsp[oc], bias[oc]));
                        y = fmaxf(y, 0.0f);
                        float v = (s == 1.0f) ? y : (y / s);
                        v = rintf(v);
                        v = fminf(fmaxf(v, 0.0f), 255.0f);
                        float o = (s == 1.0f) ? v : fminf(fmaxf(s * v, 0.0f), 255.0f);
                        const int cc = oc >> 2, r1 = (oc >> 1) & 1, r2 = oc & 1;
                        out[(size_t)(((b * 3 + cc) << 9) + (gy << 1) + r1) * 512 + (gx << 1) + r2] = o;
                    }
                }
            }
        }
    }
}

extern "C" void kernel_launch(void* const* d_in, const int* in_sizes, int n_in,
                              void* d_out, int out_size, void* d_ws, size_t ws_size,
                              hipStream_t stream) {
    const float* x       = (const float*)d_in[0];
    const float* head_w  = (const float*)d_in[1];
    const float* head_b  = (const float*)d_in[2];
    const float* head_sw = (const float*)d_in[3];
    const float* bb_w    = (const float*)d_in[4];
    const float* bb_b    = (const float*)d_in[5];
    const float* bb_sw   = (const float*)d_in[6];
    const float* tr_w    = (const float*)d_in[7];
    const float* tr_b    = (const float*)d_in[8];
    const float* tr_sw   = (const float*)d_in[9];
    const float* act_s   = (const float*)d_in[10];

    char* ws = (char*)d_ws;
    unsigned char* buf0 = (unsigned char*)ws;
    unsigned char* buf1 = buf0 + 16777216;
    unsigned char* buf2 = buf1 + 16777216;
    float* wqH = (float*)(ws + 50331648);                          // 3456 B
    signed char* WpB = (signed char*)(ws + 50331648 + 4096);       // 110592
    signed char* WpT = WpB + 110592;                               // 9216
    float* wsum = (float*)(ws + 50331648 + 4096 + 110592 + 9216);  // 1664 B
    unsigned* bar = (unsigned*)(ws + 50331648 + 4096 + 110592 + 9216 + 2048);

    prep_kernel<<<473, 256, 0, stream>>>(head_w, head_sw, bb_w, bb_sw, tr_w, tr_sw,
                                         wqH, WpB, WpT, wsum, bar);

    mega_kernel<<<dim3(8, 16, 8), 256, 0, stream>>>(
        x, wqH, head_b, head_sw, WpB, bb_b, bb_sw, WpT, tr_b, tr_sw,
        wsum, act_s, buf0, buf1, buf2, bar, (float*)d_out);
}